// Round 8
// baseline (667.335 us; speedup 1.0000x reference)
//
#include <hip/hip_runtime.h>

// GNNML3 forward. R8 = R7 with the nontemporal-load type fixed (clang ext_vector).
// Aggregation gather tier fix: h stored as TWO half-feature arrays (3.2MB each,
// 64B rows); two sequential passes each keep their half L2-resident (<4MB/XCD);
// recs loaded non-temporally so the edge stream doesn't evict the gather set.

#define Nn   50000
#define Ne   1600000
#define Gg   128
#define NEk  5
#define NINf 16
#define NCLSo 6
#define NB   196        // ceil((Nn+1)/256)
#define SPAD 41         // uint4 row stride of LDS A-tile in transform

using short8 = __attribute__((ext_vector_type(8))) short;
using f32x4  = __attribute__((ext_vector_type(4))) float;
using uint4v = __attribute__((ext_vector_type(4))) unsigned;   // nontemporal-loadable

__device__ __forceinline__ float2 bf2u(unsigned u) {
    return make_float2(__uint_as_float(u << 16), __uint_as_float(u & 0xffff0000u));
}
__device__ __forceinline__ unsigned f2bf(float a, float b) {
    unsigned ua = __float_as_uint(a), ub = __float_as_uint(b);
    ua += 0x7fffu + ((ua >> 16) & 1u);
    ub += 0x7fffu + ((ub >> 16) & 1u);
    return (ua >> 16) | (ub & 0xffff0000u);
}
__device__ __forceinline__ unsigned short f2bf1(float a) {
    unsigned ua = __float_as_uint(a);
    ua += 0x7fffu + ((ua >> 16) & 1u);
    return (unsigned short)(ua >> 16);
}

// ---------------- prep kernels ----------------

// x [Nn][16] fp32 -> hLo/hHi [Nn][16] uints (bf16x2); features >=16 are zero
__global__ void k_pad_x(const float* __restrict__ x, unsigned* __restrict__ hLo,
                        unsigned* __restrict__ hHi) {
    int i = blockIdx.x * 256 + threadIdx.x;           // over Nn*32
    if (i >= Nn * 32) return;
    int n = i >> 5, p = i & 31;
    int f0 = 2 * p;
    float v0 = (f0 < NINf) ? x[n * NINf + f0] : 0.f;
    float v1 = (f0 + 1 < NINf) ? x[n * NINf + f0 + 1] : 0.f;
    unsigned v = f2bf(v0, v1);
    if (p < 16) hLo[n * 16 + p] = v;
    else        hHi[n * 16 + (p - 16)] = v;
}

__global__ void k_pad_w1(const float* __restrict__ W1, float* __restrict__ W1p) {
    int i = blockIdx.x * 256 + threadIdx.x;           // over 5*64*64
    if (i >= NEk * 64 * 64) return;
    int h = i & 63, f = (i >> 6) & 63, k = i >> 12;
    W1p[i] = (f < NINf) ? W1[(k * NINf + f) * 64 + h] : 0.f;
}

// pack W[320][64] fp32 into MFMA B-fragment layout, split hi/lo bf16.
__global__ void k_pack_b(const float* __restrict__ W, unsigned short* __restrict__ bhi,
                         unsigned short* __restrict__ blo) {
    int i = blockIdx.x * 256 + threadIdx.x;
    if (i >= 20480) return;
    int j = i & 7, lane = (i >> 3) & 63, t2 = i >> 9;   // t2 = nt*10+kstep
    int nt = t2 / 10, kstep = t2 - nt * 10;
    int k = kstep * 32 + (lane >> 4) * 8 + j;
    int col = nt * 16 + (lane & 15);
    float v = W[k * 64 + col];
    unsigned short hi = f2bf1(v);
    float fhi = __uint_as_float(((unsigned)hi) << 16);
    bhi[i] = hi;
    blo[i] = f2bf1(v - fhi);
}

// rank[e] = arrival index within dst bucket; deg padded: counter n at deg[n*16]
__global__ void k_rank(const int* __restrict__ ei, int* __restrict__ deg,
                       int* __restrict__ rank) {
    int e = blockIdx.x * 256 + threadIdx.x;
    if (e >= Ne) return;
    rank[e] = atomicAdd(&deg[ei[Ne + e] * 16], 1);
}

// -------- 3-phase exclusive scan of padded deg -> rowstart --------

__global__ void k_blocksum(const int* __restrict__ deg, int* __restrict__ bsum) {
    __shared__ int l[256];
    int t = threadIdx.x;
    int i = blockIdx.x * 256 + t;
    l[t] = (i < Nn) ? deg[i * 16] : 0;
    __syncthreads();
    for (int off = 128; off > 0; off >>= 1) {
        if (t < off) l[t] += l[t + off];
        __syncthreads();
    }
    if (t == 0) bsum[blockIdx.x] = l[0];
}

__global__ void k_scanpart(const int* __restrict__ bsum, int* __restrict__ boff) {
    __shared__ int l[256];
    int t = threadIdx.x;
    int v = (t < NB) ? bsum[t] : 0;
    l[t] = v;
    __syncthreads();
    for (int off = 1; off < 256; off <<= 1) {
        int u = (t >= off) ? l[t - off] : 0;
        __syncthreads();
        l[t] += u;
        __syncthreads();
    }
    if (t < NB) boff[t] = l[t] - v;                   // exclusive
}

__global__ void k_scanfinal(const int* __restrict__ deg, const int* __restrict__ boff,
                            int* __restrict__ rowstart) {
    __shared__ int l[256];
    int t = threadIdx.x;
    int i = blockIdx.x * 256 + t;
    int v = (i < Nn) ? deg[i * 16] : 0;
    l[t] = v;
    __syncthreads();
    for (int off = 1; off < 256; off <<= 1) {
        int u = (t >= off) ? l[t - off] : 0;
        __syncthreads();
        l[t] += u;
        __syncthreads();
    }
    if (i <= Nn) rowstart[i] = boff[blockIdx.x] + l[t] - v;
}

// deterministic placement: 16B record {src, bf16 a0..a4} to pos
__global__ void k_place(const int* __restrict__ ei, const float* __restrict__ eattr,
                        const int* __restrict__ rowstart, const int* __restrict__ rank,
                        uint4* __restrict__ recs) {
    int e = blockIdx.x * 256 + threadIdx.x;
    if (e >= Ne) return;
    int d = ei[Ne + e];
    int pos = rowstart[d] + rank[e];
    const float* a = eattr + (size_t)e * 5;
    uint4 r;
    r.x = (unsigned)ei[e];
    r.y = f2bf(a[0], a[1]);
    r.z = f2bf(a[2], a[3]);
    r.w = f2bf(a[4], 0.f);
    recs[pos] = r;
}

// batch is sorted -> segment bounds by boundary detection
__global__ void k_bounds(const int* __restrict__ batch, int* __restrict__ sg,
                         int* __restrict__ eg) {
    int n = blockIdx.x * 256 + threadIdx.x;
    if (n >= Nn) return;
    int g = batch[n];
    if (n == 0) sg[g] = 0;
    else {
        int gp = batch[n - 1];
        if (gp != g) { sg[g] = n; eg[gp] = n; }
    }
    if (n == Nn - 1) eg[g] = Nn;
}

// ---------------- per-layer kernels ----------------

// Half-feature aggregation pass. One wave per node; QUARTER-wave (16 lanes) per
// edge -> one 64B sector per gather; 16 edges in flight per wave. recs loaded
// non-temporally (streaming) so the 3.2MB hin half stays L2-resident.
__global__ __launch_bounds__(256) void k_aggregate_half(
    const unsigned* __restrict__ hin, const int* __restrict__ rowstart,
    const uint4v* __restrict__ recs, unsigned* __restrict__ agg, int halfSel) {
    int lane = threadIdx.x & 63;
    int l = lane & 15, q = lane >> 4;                  // quarter 0..3
    int node = __builtin_amdgcn_readfirstlane((int)(blockIdx.x * 4 + (threadIdx.x >> 6)));
    int beg = rowstart[node], end = rowstart[node + 1];
    float2 c0 = {0.f, 0.f}, c1 = c0, c2 = c0, c3 = c0, c4 = c0;
    int ee = beg;
#define EDGE(E) { \
    uint4v r = __builtin_nontemporal_load(&recs[(E)]); \
    unsigned hx = hin[(size_t)(int)r.x * 16 + l]; \
    float2 xv = bf2u(hx); \
    float2 A01 = bf2u(r.y), A23 = bf2u(r.z); \
    float a4v = __uint_as_float(r.w << 16); \
    c0.x = fmaf(A01.x, xv.x, c0.x); c0.y = fmaf(A01.x, xv.y, c0.y); \
    c1.x = fmaf(A01.y, xv.x, c1.x); c1.y = fmaf(A01.y, xv.y, c1.y); \
    c2.x = fmaf(A23.x, xv.x, c2.x); c2.y = fmaf(A23.x, xv.y, c2.y); \
    c3.x = fmaf(A23.y, xv.x, c3.x); c3.y = fmaf(A23.y, xv.y, c3.y); \
    c4.x = fmaf(a4v,  xv.x, c4.x); c4.y = fmaf(a4v,  xv.y, c4.y); }
    for (; ee + 16 <= end; ee += 16) {
        EDGE(ee + q) EDGE(ee + 4 + q) EDGE(ee + 8 + q) EDGE(ee + 12 + q)
    }
    for (; ee + 4 <= end; ee += 4) { EDGE(ee + q) }
    int rem = end - ee;
    if (q < rem) { EDGE(ee + q) }
#undef EDGE
    // butterfly-fold the 4 quarters (every lane ends with the node total)
    c0.x += __shfl(c0.x, lane ^ 16); c0.y += __shfl(c0.y, lane ^ 16);
    c1.x += __shfl(c1.x, lane ^ 16); c1.y += __shfl(c1.y, lane ^ 16);
    c2.x += __shfl(c2.x, lane ^ 16); c2.y += __shfl(c2.y, lane ^ 16);
    c3.x += __shfl(c3.x, lane ^ 16); c3.y += __shfl(c3.y, lane ^ 16);
    c4.x += __shfl(c4.x, lane ^ 16); c4.y += __shfl(c4.y, lane ^ 16);
    c0.x += __shfl(c0.x, lane ^ 32); c0.y += __shfl(c0.y, lane ^ 32);
    c1.x += __shfl(c1.x, lane ^ 32); c1.y += __shfl(c1.y, lane ^ 32);
    c2.x += __shfl(c2.x, lane ^ 32); c2.y += __shfl(c2.y, lane ^ 32);
    c3.x += __shfl(c3.x, lane ^ 32); c3.y += __shfl(c3.y, lane ^ 32);
    c4.x += __shfl(c4.x, lane ^ 32); c4.y += __shfl(c4.y, lane ^ 32);
    if (q == 0) {
        unsigned* o = agg + (size_t)node * 160 + halfSel * 16 + l;
        o[0]   = f2bf(c0.x, c0.y);
        o[32]  = f2bf(c1.x, c1.y);
        o[64]  = f2bf(c2.x, c2.y);
        o[96]  = f2bf(c3.x, c3.y);
        o[128] = f2bf(c4.x, c4.y);
    }
}

// MFMA transform: [64 nodes x 320]bf16 x (Whi+Wlo)[320 x 64] + bias, relu ->
// bf16 written as split lo/hi half-feature arrays.
__global__ __launch_bounds__(256) void k_transform(
    const uint4* __restrict__ A, const unsigned short* __restrict__ bhi,
    const unsigned short* __restrict__ blo, const float* __restrict__ bias,
    unsigned* __restrict__ outLo, unsigned* __restrict__ outHi) {
    __shared__ uint4 smem[64 * SPAD];                  // 41984 B
    int t = threadIdx.x;
    int lane = t & 63, wave = t >> 6;
    int m = lane & 15, quad = lane >> 4;
    int blk = blockIdx.x;

#pragma unroll
    for (int it = 0; it < 10; ++it) {
        int v = t + it * 256;                          // 0..2559
        int row = v / 40, off = v - row * 40;
        int node = blk * 64 + row;
        if (node >= Nn) node = Nn - 1;
        smem[row * SPAD + off] = A[(size_t)node * 40 + off];
    }
    __syncthreads();

    f32x4 acc0 = {0.f, 0.f, 0.f, 0.f}, acc1 = acc0, acc2 = acc0, acc3 = acc0;
    const uint4* arow = smem + (wave * 16 + m) * SPAD + quad;
#pragma unroll 2
    for (int ks = 0; ks < 10; ++ks) {
        short8 a = *(const short8*)(arow + ks * 4);
        size_t bb = ((size_t)ks * 64 + lane) * 8;      // + nt*5120
        short8 h0 = *(const short8*)(bhi + bb);
        short8 l0 = *(const short8*)(blo + bb);
        acc0 = __builtin_amdgcn_mfma_f32_16x16x32_bf16(a, h0, acc0, 0, 0, 0);
        acc0 = __builtin_amdgcn_mfma_f32_16x16x32_bf16(a, l0, acc0, 0, 0, 0);
        short8 h1 = *(const short8*)(bhi + bb + 5120);
        short8 l1 = *(const short8*)(blo + bb + 5120);
        acc1 = __builtin_amdgcn_mfma_f32_16x16x32_bf16(a, h1, acc1, 0, 0, 0);
        acc1 = __builtin_amdgcn_mfma_f32_16x16x32_bf16(a, l1, acc1, 0, 0, 0);
        short8 h2 = *(const short8*)(bhi + bb + 10240);
        short8 l2 = *(const short8*)(blo + bb + 10240);
        acc2 = __builtin_amdgcn_mfma_f32_16x16x32_bf16(a, h2, acc2, 0, 0, 0);
        acc2 = __builtin_amdgcn_mfma_f32_16x16x32_bf16(a, l2, acc2, 0, 0, 0);
        short8 h3 = *(const short8*)(bhi + bb + 15360);
        short8 l3 = *(const short8*)(blo + bb + 15360);
        acc3 = __builtin_amdgcn_mfma_f32_16x16x32_bf16(a, h3, acc3, 0, 0, 0);
        acc3 = __builtin_amdgcn_mfma_f32_16x16x32_bf16(a, l3, acc3, 0, 0, 0);
    }
    __syncthreads();                                   // A-tile reads done

    // C layout (16x16x32): col=lane&15, row=quad*4+reg -> spill to LDS fp32 [64][72]
    float* Cs = (float*)smem;
#pragma unroll
    for (int r = 0; r < 4; ++r) {
        int base = wave * 1152 + (quad * 4 + r) * 72 + m;
        Cs[base]      = acc0[r];
        Cs[base + 16] = acc1[r];
        Cs[base + 32] = acc2[r];
        Cs[base + 48] = acc3[r];
    }
    __syncthreads();

    int row = t >> 2, grp = t & 3;                     // 4 threads/row, 8 uints each
    int node = blk * 64 + row;
    if (node < Nn) {
        const float* cr = Cs + (row >> 4) * 1152 + (row & 15) * 72;
        unsigned o[8];
#pragma unroll
        for (int j = 0; j < 8; ++j) {
            int pp = grp * 8 + j;
            float v0 = fmaxf(cr[2 * pp]     + bias[2 * pp],     0.f);
            float v1 = fmaxf(cr[2 * pp + 1] + bias[2 * pp + 1], 0.f);
            o[j] = f2bf(v0, v1);
        }
        unsigned* dstArr = (grp < 2) ? outLo : outHi;
        uint4* dst = (uint4*)(dstArr + (size_t)node * 16 + (grp & 1) * 8);
        dst[0] = make_uint4(o[0], o[1], o[2], o[3]);
        dst[1] = make_uint4(o[4], o[5], o[6], o[7]);
    }
}

// ---------------- pooling + head ----------------

__global__ __launch_bounds__(256) void k_pool(const unsigned* __restrict__ hLo,
                                              const unsigned* __restrict__ hHi,
                                              const int* __restrict__ sg,
                                              const int* __restrict__ eg,
                                              float* __restrict__ pooled) {
    __shared__ float2 ls[256], lm[256];
    int g = blockIdx.x, t = threadIdx.x;
    int p = t & 31, q = t >> 5;                        // 32 feature-pairs x 8 node-strides
    int s = sg[g], e = eg[g];
    const unsigned* harr = (p < 16) ? hLo : hHi;
    int po = p & 15;
    float2 sum = {0.f, 0.f}, mx = {0.f, 0.f};          // relu>=0 -> 0 valid max identity
    for (int n = s + q; n < e; n += 8) {
        float2 v = bf2u(harr[(size_t)n * 16 + po]);
        sum.x += v.x; sum.y += v.y;
        mx.x = fmaxf(mx.x, v.x); mx.y = fmaxf(mx.y, v.y);
    }
    ls[t] = sum; lm[t] = mx;
    __syncthreads();
    if (t < 32) {
        float2 ss = ls[t], mm = lm[t];
        for (int i = 1; i < 8; ++i) {
            float2 a = ls[t + i * 32], b = lm[t + i * 32];
            ss.x += a.x; ss.y += a.y;
            mm.x = fmaxf(mm.x, b.x); mm.y = fmaxf(mm.y, b.y);
        }
        pooled[g * 128 + 2 * t]          = ss.x;
        pooled[g * 128 + 2 * t + 1]      = ss.y;
        pooled[g * 128 + 64 + 2 * t]     = mm.x;
        pooled[g * 128 + 64 + 2 * t + 1] = mm.y;
    }
}

__global__ void k_head(const float* __restrict__ pooled, const float* __restrict__ gamma,
                       const float* __restrict__ beta, const float* __restrict__ mean,
                       const float* __restrict__ var, const float* __restrict__ fcw,
                       const float* __restrict__ fcb, float* __restrict__ out) {
    __shared__ float y[128];
    __shared__ float lg[8];
    int g = blockIdx.x, c = threadIdx.x;   // 128 threads
    float p = pooled[g * 128 + c];
    y[c] = (p - mean[c]) * rsqrtf(var[c] + 1e-5f) * gamma[c] + beta[c];
    __syncthreads();
    if (c < NCLSo) {
        float l = fcb[c];
        for (int i = 0; i < 128; ++i) l += y[i] * fcw[i * NCLSo + c];
        lg[c] = l;
    }
    __syncthreads();
    if (c == 0) {
        float m = lg[0];
        for (int j = 1; j < NCLSo; ++j) m = fmaxf(m, lg[j]);
        float se = 0.f;
        for (int j = 0; j < NCLSo; ++j) se += expf(lg[j] - m);
        float lse = m + logf(se);
        for (int j = 0; j < NCLSo; ++j) out[g * NCLSo + j] = lg[j] - lse;
    }
}

// ---------------- launch ----------------

static inline size_t rup(size_t x) { return (x + 255) & ~(size_t)255; }

extern "C" void kernel_launch(void* const* d_in, const int* in_sizes, int n_in,
                              void* d_out, int out_size, void* d_ws, size_t ws_size,
                              hipStream_t stream) {
    const float* x     = (const float*)d_in[0];
    const int*   ei    = (const int*)d_in[1];
    const float* eattr = (const float*)d_in[2];
    const int*   batch = (const int*)d_in[3];
    const float* W1    = (const float*)d_in[4];
    const float* b1    = (const float*)d_in[5];
    const float* W2    = (const float*)d_in[6];
    const float* b2    = (const float*)d_in[7];
    const float* W3    = (const float*)d_in[8];
    const float* b3    = (const float*)d_in[9];
    const float* W4    = (const float*)d_in[10];
    const float* b4    = (const float*)d_in[11];
    const float* gamma = (const float*)d_in[12];
    const float* beta  = (const float*)d_in[13];
    const float* mean  = (const float*)d_in[14];
    const float* var   = (const float*)d_in[15];
    const float* fcw   = (const float*)d_in[16];
    const float* fcb   = (const float*)d_in[17];
    float* out = (float*)d_out;

    char* p = (char*)d_ws;
    auto take = [&](size_t bytes) { char* r = p; p += rup(bytes); return r; };
    int*            deg      = (int*)take((size_t)(Nn + 1) * 64);   // padded: 1 counter/64B
    int*            rowstart = (int*)take((size_t)(Nn + 1) * 4);
    int*            bsum     = (int*)take((size_t)NB * 4);
    int*            boff     = (int*)take((size_t)NB * 4);
    int*            rank     = (int*)take((size_t)Ne * 4);
    uint4*          recs     = (uint4*)take((size_t)Ne * 16);
    unsigned*       hLoA     = (unsigned*)take((size_t)Nn * 16 * 4);
    unsigned*       hHiA     = (unsigned*)take((size_t)Nn * 16 * 4);
    unsigned*       hLoB     = (unsigned*)take((size_t)Nn * 16 * 4);
    unsigned*       hHiB     = (unsigned*)take((size_t)Nn * 16 * 4);
    unsigned*       agg      = (unsigned*)take((size_t)Nn * 160 * 4);
    float*          W1p      = (float*)take((size_t)NEk * 64 * 64 * 4);
    unsigned short* bhiA     = (unsigned short*)take((size_t)4 * 20480 * 2);
    unsigned short* bloA     = (unsigned short*)take((size_t)4 * 20480 * 2);
    float*          pooled   = (float*)take((size_t)Gg * 128 * 4);
    int*            sg       = (int*)take((size_t)Gg * 4);
    int*            eg       = (int*)take((size_t)Gg * 4);

    (void)hipMemsetAsync(deg, 0, (size_t)(Nn + 1) * 64, stream);

    k_pad_x<<<(Nn * 32 + 255) / 256, 256, 0, stream>>>(x, hLoA, hHiA);
    k_pad_w1<<<(NEk * 64 * 64 + 255) / 256, 256, 0, stream>>>(W1, W1p);
    k_pack_b<<<80, 256, 0, stream>>>(W1p, bhiA,             bloA);
    k_pack_b<<<80, 256, 0, stream>>>(W2,  bhiA + 20480,     bloA + 20480);
    k_pack_b<<<80, 256, 0, stream>>>(W3,  bhiA + 2 * 20480, bloA + 2 * 20480);
    k_pack_b<<<80, 256, 0, stream>>>(W4,  bhiA + 3 * 20480, bloA + 3 * 20480);
    k_rank<<<(Ne + 255) / 256, 256, 0, stream>>>(ei, deg, rank);
    k_blocksum<<<NB, 256, 0, stream>>>(deg, bsum);
    k_scanpart<<<1, 256, 0, stream>>>(bsum, boff);
    k_scanfinal<<<NB, 256, 0, stream>>>(deg, boff, rowstart);
    k_place<<<(Ne + 255) / 256, 256, 0, stream>>>(ei, eattr, rowstart, rank, recs);
    k_bounds<<<(Nn + 255) / 256, 256, 0, stream>>>(batch, sg, eg);

    const float* bs[4] = { b1, b2, b3, b4 };
    unsigned *curLo = hLoA, *curHi = hHiA, *nxtLo = hLoB, *nxtHi = hHiB;
    for (int L = 0; L < 4; ++L) {
        k_aggregate_half<<<Nn / 4, 256, 0, stream>>>(curLo, rowstart,
                                                     (const uint4v*)recs, agg, 0);
        k_aggregate_half<<<Nn / 4, 256, 0, stream>>>(curHi, rowstart,
                                                     (const uint4v*)recs, agg, 1);
        k_transform<<<(Nn + 63) / 64, 256, 0, stream>>>(
            (const uint4*)agg, bhiA + (size_t)L * 20480, bloA + (size_t)L * 20480,
            bs[L], nxtLo, nxtHi);
        unsigned* t0 = curLo; curLo = nxtLo; nxtLo = t0;
        unsigned* t1 = curHi; curHi = nxtHi; nxtHi = t1;
    }

    k_pool<<<Gg, 256, 0, stream>>>(curLo, curHi, sg, eg, pooled);
    k_head<<<Gg, 128, 0, stream>>>(pooled, gamma, beta, mean, var, fcw, fcb, out);
}

// Round 9
// 575.654 us; speedup vs baseline: 1.1593x; 1.1593x over previous
//
#include <hip/hip_runtime.h>

// GNNML3 forward. R9 = R5 structure (best measured) + padded deg (R6) +
// aggregate edge-loop unrolled to 16 edges in flight per wave (MLP attack:
// the aggregate is latency-bound on recs->gather dependent chains, not
// capacity- or VALU-bound — R8 falsified the L2-residency theory).

#define Nn   50000
#define Ne   1600000
#define Gg   128
#define NEk  5
#define NINf 16
#define NCLSo 6
#define NB   196        // ceil((Nn+1)/256)
#define SPAD 41         // uint4 row stride of LDS A-tile in transform

using short8 = __attribute__((ext_vector_type(8))) short;
using f32x4  = __attribute__((ext_vector_type(4))) float;
using uint4v = __attribute__((ext_vector_type(4))) unsigned;

__device__ __forceinline__ float2 bf2u(unsigned u) {
    return make_float2(__uint_as_float(u << 16), __uint_as_float(u & 0xffff0000u));
}
__device__ __forceinline__ unsigned f2bf(float a, float b) {
    unsigned ua = __float_as_uint(a), ub = __float_as_uint(b);
    ua += 0x7fffu + ((ua >> 16) & 1u);
    ub += 0x7fffu + ((ub >> 16) & 1u);
    return (ua >> 16) | (ub & 0xffff0000u);
}
__device__ __forceinline__ unsigned short f2bf1(float a) {
    unsigned ua = __float_as_uint(a);
    ua += 0x7fffu + ((ua >> 16) & 1u);
    return (unsigned short)(ua >> 16);
}

// ---------------- prep kernels ----------------

// x [Nn][16] fp32 -> h0 [Nn][32] uint (bf16x2 pairs, features >=16 zero)
__global__ void k_pad_x(const float* __restrict__ x, unsigned* __restrict__ h0) {
    int i = blockIdx.x * 256 + threadIdx.x;           // over Nn*32
    if (i >= Nn * 32) return;
    int n = i >> 5, p = i & 31;
    int f0 = 2 * p;
    float v0 = (f0 < NINf) ? x[n * NINf + f0] : 0.f;
    float v1 = (f0 + 1 < NINf) ? x[n * NINf + f0 + 1] : 0.f;
    h0[i] = f2bf(v0, v1);
}

__global__ void k_pad_w1(const float* __restrict__ W1, float* __restrict__ W1p) {
    int i = blockIdx.x * 256 + threadIdx.x;           // over 5*64*64
    if (i >= NEk * 64 * 64) return;
    int h = i & 63, f = (i >> 6) & 63, k = i >> 12;
    W1p[i] = (f < NINf) ? W1[(k * NINf + f) * 64 + h] : 0.f;
}

// pack W[320][64] fp32 into MFMA B-fragment layout, split hi/lo bf16.
__global__ void k_pack_b(const float* __restrict__ W, unsigned short* __restrict__ bhi,
                         unsigned short* __restrict__ blo) {
    int i = blockIdx.x * 256 + threadIdx.x;
    if (i >= 20480) return;
    int j = i & 7, lane = (i >> 3) & 63, t2 = i >> 9;   // t2 = nt*10+kstep
    int nt = t2 / 10, kstep = t2 - nt * 10;
    int k = kstep * 32 + (lane >> 4) * 8 + j;
    int col = nt * 16 + (lane & 15);
    float v = W[k * 64 + col];
    unsigned short hi = f2bf1(v);
    float fhi = __uint_as_float(((unsigned)hi) << 16);
    bhi[i] = hi;
    blo[i] = f2bf1(v - fhi);
}

// rank[e] = arrival index within dst bucket; deg padded: counter n at deg[n*16]
__global__ void k_rank(const int* __restrict__ ei, int* __restrict__ deg,
                       int* __restrict__ rank) {
    int e = blockIdx.x * 256 + threadIdx.x;
    if (e >= Ne) return;
    rank[e] = atomicAdd(&deg[ei[Ne + e] * 16], 1);
}

// -------- 3-phase exclusive scan of padded deg -> rowstart --------

__global__ void k_blocksum(const int* __restrict__ deg, int* __restrict__ bsum) {
    __shared__ int l[256];
    int t = threadIdx.x;
    int i = blockIdx.x * 256 + t;
    l[t] = (i < Nn) ? deg[i * 16] : 0;
    __syncthreads();
    for (int off = 128; off > 0; off >>= 1) {
        if (t < off) l[t] += l[t + off];
        __syncthreads();
    }
    if (t == 0) bsum[blockIdx.x] = l[0];
}

__global__ void k_scanpart(const int* __restrict__ bsum, int* __restrict__ boff) {
    __shared__ int l[256];
    int t = threadIdx.x;
    int v = (t < NB) ? bsum[t] : 0;
    l[t] = v;
    __syncthreads();
    for (int off = 1; off < 256; off <<= 1) {
        int u = (t >= off) ? l[t - off] : 0;
        __syncthreads();
        l[t] += u;
        __syncthreads();
    }
    if (t < NB) boff[t] = l[t] - v;                   // exclusive
}

__global__ void k_scanfinal(const int* __restrict__ deg, const int* __restrict__ boff,
                            int* __restrict__ rowstart) {
    __shared__ int l[256];
    int t = threadIdx.x;
    int i = blockIdx.x * 256 + t;
    int v = (i < Nn) ? deg[i * 16] : 0;
    l[t] = v;
    __syncthreads();
    for (int off = 1; off < 256; off <<= 1) {
        int u = (t >= off) ? l[t - off] : 0;
        __syncthreads();
        l[t] += u;
        __syncthreads();
    }
    if (i <= Nn) rowstart[i] = boff[blockIdx.x] + l[t] - v;
}

// deterministic placement: 16B record {src, bf16 a0..a4} to pos (nontemporal)
__global__ void k_place(const int* __restrict__ ei, const float* __restrict__ eattr,
                        const int* __restrict__ rowstart, const int* __restrict__ rank,
                        uint4v* __restrict__ recs) {
    int e = blockIdx.x * 256 + threadIdx.x;
    if (e >= Ne) return;
    int d = ei[Ne + e];
    int pos = rowstart[d] + rank[e];
    const float* a = eattr + (size_t)e * 5;
    uint4v r;
    r.x = (unsigned)ei[e];
    r.y = f2bf(a[0], a[1]);
    r.z = f2bf(a[2], a[3]);
    r.w = f2bf(a[4], 0.f);
    __builtin_nontemporal_store(r, &recs[pos]);
}

// batch is sorted -> segment bounds by boundary detection
__global__ void k_bounds(const int* __restrict__ batch, int* __restrict__ sg,
                         int* __restrict__ eg) {
    int n = blockIdx.x * 256 + threadIdx.x;
    if (n >= Nn) return;
    int g = batch[n];
    if (n == 0) sg[g] = 0;
    else {
        int gp = batch[n - 1];
        if (gp != g) { sg[g] = n; eg[gp] = n; }
    }
    if (n == Nn - 1) eg[g] = Nn;
}

// ---------------- per-layer kernels ----------------

// one wave per node; half-wave (32 lanes) per edge, 2 features (bf16x2) per lane.
// unroll x8 -> 16 edges (8 independent recs->gather chains per half) in flight.
__global__ __launch_bounds__(256) void k_aggregate(
    const unsigned* __restrict__ hin, const int* __restrict__ rowstart,
    const uint4* __restrict__ recs, unsigned* __restrict__ agg) {
    int lane = threadIdx.x & 63;
    int l = lane & 31, half = lane >> 5;
    int node = __builtin_amdgcn_readfirstlane((int)(blockIdx.x * 4 + (threadIdx.x >> 6)));
    int beg = rowstart[node], end = rowstart[node + 1];
    float2 c0 = {0.f, 0.f}, c1 = c0, c2 = c0, c3 = c0, c4 = c0;
    int ee = beg;
#define EDGE(E) { \
    uint4 r = recs[(E)]; \
    unsigned hx = hin[(size_t)(int)r.x * 32 + l]; \
    float2 xv = bf2u(hx); \
    float2 A01 = bf2u(r.y), A23 = bf2u(r.z); \
    float a4v = __uint_as_float(r.w << 16); \
    c0.x = fmaf(A01.x, xv.x, c0.x); c0.y = fmaf(A01.x, xv.y, c0.y); \
    c1.x = fmaf(A01.y, xv.x, c1.x); c1.y = fmaf(A01.y, xv.y, c1.y); \
    c2.x = fmaf(A23.x, xv.x, c2.x); c2.y = fmaf(A23.x, xv.y, c2.y); \
    c3.x = fmaf(A23.y, xv.x, c3.x); c3.y = fmaf(A23.y, xv.y, c3.y); \
    c4.x = fmaf(a4v,  xv.x, c4.x); c4.y = fmaf(a4v,  xv.y, c4.y); }
    for (; ee + 16 <= end; ee += 16) {
        EDGE(ee + half)      EDGE(ee + 2 + half)  EDGE(ee + 4 + half)  EDGE(ee + 6 + half)
        EDGE(ee + 8 + half)  EDGE(ee + 10 + half) EDGE(ee + 12 + half) EDGE(ee + 14 + half)
    }
    for (; ee + 4 <= end; ee += 4) { EDGE(ee + half) EDGE(ee + 2 + half) }
    for (; ee + 2 <= end; ee += 2) { EDGE(ee + half) }
    if (ee < end) { if (half == 0) { EDGE(ee) } }
#undef EDGE
    // fold half 1 into half 0 (xor-butterfly, both halves end with the total)
    c0.x += __shfl(c0.x, lane ^ 32); c0.y += __shfl(c0.y, lane ^ 32);
    c1.x += __shfl(c1.x, lane ^ 32); c1.y += __shfl(c1.y, lane ^ 32);
    c2.x += __shfl(c2.x, lane ^ 32); c2.y += __shfl(c2.y, lane ^ 32);
    c3.x += __shfl(c3.x, lane ^ 32); c3.y += __shfl(c3.y, lane ^ 32);
    c4.x += __shfl(c4.x, lane ^ 32); c4.y += __shfl(c4.y, lane ^ 32);
    if (half == 0) {
        unsigned* o = agg + (size_t)node * 160 + l;
        o[0]   = f2bf(c0.x, c0.y);
        o[32]  = f2bf(c1.x, c1.y);
        o[64]  = f2bf(c2.x, c2.y);
        o[96]  = f2bf(c3.x, c3.y);
        o[128] = f2bf(c4.x, c4.y);
    }
}

// MFMA transform: [64 nodes x 320]bf16 x (Whi+Wlo)[320 x 64] + bias, relu -> bf16.
__global__ __launch_bounds__(256) void k_transform(
    const uint4* __restrict__ A, const unsigned short* __restrict__ bhi,
    const unsigned short* __restrict__ blo, const float* __restrict__ bias,
    unsigned* __restrict__ outh) {
    __shared__ uint4 smem[64 * SPAD];                  // 41984 B
    int t = threadIdx.x;
    int lane = t & 63, wave = t >> 6;
    int m = lane & 15, quad = lane >> 4;
    int blk = blockIdx.x;

#pragma unroll
    for (int it = 0; it < 10; ++it) {
        int v = t + it * 256;                          // 0..2559
        int row = v / 40, off = v - row * 40;
        int node = blk * 64 + row;
        if (node >= Nn) node = Nn - 1;
        smem[row * SPAD + off] = A[(size_t)node * 40 + off];
    }
    __syncthreads();

    f32x4 acc0 = {0.f, 0.f, 0.f, 0.f}, acc1 = acc0, acc2 = acc0, acc3 = acc0;
    const uint4* arow = smem + (wave * 16 + m) * SPAD + quad;
#pragma unroll 2
    for (int ks = 0; ks < 10; ++ks) {
        short8 a = *(const short8*)(arow + ks * 4);
        size_t bb = ((size_t)ks * 64 + lane) * 8;      // + nt*5120
        short8 h0 = *(const short8*)(bhi + bb);
        short8 l0 = *(const short8*)(blo + bb);
        acc0 = __builtin_amdgcn_mfma_f32_16x16x32_bf16(a, h0, acc0, 0, 0, 0);
        acc0 = __builtin_amdgcn_mfma_f32_16x16x32_bf16(a, l0, acc0, 0, 0, 0);
        short8 h1 = *(const short8*)(bhi + bb + 5120);
        short8 l1 = *(const short8*)(blo + bb + 5120);
        acc1 = __builtin_amdgcn_mfma_f32_16x16x32_bf16(a, h1, acc1, 0, 0, 0);
        acc1 = __builtin_amdgcn_mfma_f32_16x16x32_bf16(a, l1, acc1, 0, 0, 0);
        short8 h2 = *(const short8*)(bhi + bb + 10240);
        short8 l2 = *(const short8*)(blo + bb + 10240);
        acc2 = __builtin_amdgcn_mfma_f32_16x16x32_bf16(a, h2, acc2, 0, 0, 0);
        acc2 = __builtin_amdgcn_mfma_f32_16x16x32_bf16(a, l2, acc2, 0, 0, 0);
        short8 h3 = *(const short8*)(bhi + bb + 15360);
        short8 l3 = *(const short8*)(blo + bb + 15360);
        acc3 = __builtin_amdgcn_mfma_f32_16x16x32_bf16(a, h3, acc3, 0, 0, 0);
        acc3 = __builtin_amdgcn_mfma_f32_16x16x32_bf16(a, l3, acc3, 0, 0, 0);
    }
    __syncthreads();                                   // A-tile reads done

    // C layout (16x16x32): col=lane&15, row=quad*4+reg -> spill to LDS fp32 [64][72]
    float* Cs = (float*)smem;
#pragma unroll
    for (int r = 0; r < 4; ++r) {
        int base = wave * 1152 + (quad * 4 + r) * 72 + m;
        Cs[base]      = acc0[r];
        Cs[base + 16] = acc1[r];
        Cs[base + 32] = acc2[r];
        Cs[base + 48] = acc3[r];
    }
    __syncthreads();

    int row = t >> 2, grp = t & 3;                     // 4 threads/row, 8 uints each
    int node = blk * 64 + row;
    if (node < Nn) {
        const float* cr = Cs + (row >> 4) * 1152 + (row & 15) * 72;
        unsigned o[8];
#pragma unroll
        for (int j = 0; j < 8; ++j) {
            int pp = grp * 8 + j;
            float v0 = fmaxf(cr[2 * pp]     + bias[2 * pp],     0.f);
            float v1 = fmaxf(cr[2 * pp + 1] + bias[2 * pp + 1], 0.f);
            o[j] = f2bf(v0, v1);
        }
        uint4* dst = (uint4*)(outh + (size_t)node * 32 + grp * 8);
        dst[0] = make_uint4(o[0], o[1], o[2], o[3]);
        dst[1] = make_uint4(o[4], o[5], o[6], o[7]);
    }
}

// ---------------- pooling + head ----------------

__global__ __launch_bounds__(256) void k_pool(const unsigned* __restrict__ h,
                                              const int* __restrict__ sg,
                                              const int* __restrict__ eg,
                                              float* __restrict__ pooled) {
    __shared__ float2 ls[256], lm[256];
    int g = blockIdx.x, t = threadIdx.x;
    int p = t & 31, q = t >> 5;                        // 32 feature-pairs x 8 node-strides
    int s = sg[g], e = eg[g];
    float2 sum = {0.f, 0.f}, mx = {0.f, 0.f};          // relu>=0 -> 0 valid max identity
    for (int n = s + q; n < e; n += 8) {
        float2 v = bf2u(h[(size_t)n * 32 + p]);
        sum.x += v.x; sum.y += v.y;
        mx.x = fmaxf(mx.x, v.x); mx.y = fmaxf(mx.y, v.y);
    }
    ls[t] = sum; lm[t] = mx;
    __syncthreads();
    if (t < 32) {
        float2 ss = ls[t], mm = lm[t];
        for (int i = 1; i < 8; ++i) {
            float2 a = ls[t + i * 32], b = lm[t + i * 32];
            ss.x += a.x; ss.y += a.y;
            mm.x = fmaxf(mm.x, b.x); mm.y = fmaxf(mm.y, b.y);
        }
        pooled[g * 128 + 2 * t]          = ss.x;
        pooled[g * 128 + 2 * t + 1]      = ss.y;
        pooled[g * 128 + 64 + 2 * t]     = mm.x;
        pooled[g * 128 + 64 + 2 * t + 1] = mm.y;
    }
}

__global__ void k_head(const float* __restrict__ pooled, const float* __restrict__ gamma,
                       const float* __restrict__ beta, const float* __restrict__ mean,
                       const float* __restrict__ var, const float* __restrict__ fcw,
                       const float* __restrict__ fcb, float* __restrict__ out) {
    __shared__ float y[128];
    __shared__ float lg[8];
    int g = blockIdx.x, c = threadIdx.x;   // 128 threads
    float p = pooled[g * 128 + c];
    y[c] = (p - mean[c]) * rsqrtf(var[c] + 1e-5f) * gamma[c] + beta[c];
    __syncthreads();
    if (c < NCLSo) {
        float l = fcb[c];
        for (int i = 0; i < 128; ++i) l += y[i] * fcw[i * NCLSo + c];
        lg[c] = l;
    }
    __syncthreads();
    if (c == 0) {
        float m = lg[0];
        for (int j = 1; j < NCLSo; ++j) m = fmaxf(m, lg[j]);
        float se = 0.f;
        for (int j = 0; j < NCLSo; ++j) se += expf(lg[j] - m);
        float lse = m + logf(se);
        for (int j = 0; j < NCLSo; ++j) out[g * NCLSo + j] = lg[j] - lse;
    }
}

// ---------------- launch ----------------

static inline size_t rup(size_t x) { return (x + 255) & ~(size_t)255; }

extern "C" void kernel_launch(void* const* d_in, const int* in_sizes, int n_in,
                              void* d_out, int out_size, void* d_ws, size_t ws_size,
                              hipStream_t stream) {
    const float* x     = (const float*)d_in[0];
    const int*   ei    = (const int*)d_in[1];
    const float* eattr = (const float*)d_in[2];
    const int*   batch = (const int*)d_in[3];
    const float* W1    = (const float*)d_in[4];
    const float* b1    = (const float*)d_in[5];
    const float* W2    = (const float*)d_in[6];
    const float* b2    = (const float*)d_in[7];
    const float* W3    = (const float*)d_in[8];
    const float* b3    = (const float*)d_in[9];
    const float* W4    = (const float*)d_in[10];
    const float* b4    = (const float*)d_in[11];
    const float* gamma = (const float*)d_in[12];
    const float* beta  = (const float*)d_in[13];
    const float* mean  = (const float*)d_in[14];
    const float* var   = (const float*)d_in[15];
    const float* fcw   = (const float*)d_in[16];
    const float* fcb   = (const float*)d_in[17];
    float* out = (float*)d_out;

    char* p = (char*)d_ws;
    auto take = [&](size_t bytes) { char* r = p; p += rup(bytes); return r; };
    int*            deg      = (int*)take((size_t)(Nn + 1) * 64);   // padded: 1 counter/64B
    int*            rowstart = (int*)take((size_t)(Nn + 1) * 4);
    int*            bsum     = (int*)take((size_t)NB * 4);
    int*            boff     = (int*)take((size_t)NB * 4);
    int*            rank     = (int*)take((size_t)Ne * 4);
    uint4*          recs     = (uint4*)take((size_t)Ne * 16);
    unsigned*       hA       = (unsigned*)take((size_t)Nn * 32 * 4);
    unsigned*       hB       = (unsigned*)take((size_t)Nn * 32 * 4);
    unsigned*       agg      = (unsigned*)take((size_t)Nn * 160 * 4);
    float*          W1p      = (float*)take((size_t)NEk * 64 * 64 * 4);
    unsigned short* bhiA     = (unsigned short*)take((size_t)4 * 20480 * 2);
    unsigned short* bloA     = (unsigned short*)take((size_t)4 * 20480 * 2);
    float*          pooled   = (float*)take((size_t)Gg * 128 * 4);
    int*            sg       = (int*)take((size_t)Gg * 4);
    int*            eg       = (int*)take((size_t)Gg * 4);

    (void)hipMemsetAsync(deg, 0, (size_t)(Nn + 1) * 64, stream);

    k_pad_x<<<(Nn * 32 + 255) / 256, 256, 0, stream>>>(x, hA);
    k_pad_w1<<<(NEk * 64 * 64 + 255) / 256, 256, 0, stream>>>(W1, W1p);
    k_pack_b<<<80, 256, 0, stream>>>(W1p, bhiA,             bloA);
    k_pack_b<<<80, 256, 0, stream>>>(W2,  bhiA + 20480,     bloA + 20480);
    k_pack_b<<<80, 256, 0, stream>>>(W3,  bhiA + 2 * 20480, bloA + 2 * 20480);
    k_pack_b<<<80, 256, 0, stream>>>(W4,  bhiA + 3 * 20480, bloA + 3 * 20480);
    k_rank<<<(Ne + 255) / 256, 256, 0, stream>>>(ei, deg, rank);
    k_blocksum<<<NB, 256, 0, stream>>>(deg, bsum);
    k_scanpart<<<1, 256, 0, stream>>>(bsum, boff);
    k_scanfinal<<<NB, 256, 0, stream>>>(deg, boff, rowstart);
    k_place<<<(Ne + 255) / 256, 256, 0, stream>>>(ei, eattr, rowstart, rank,
                                                  (uint4v*)recs);
    k_bounds<<<(Nn + 255) / 256, 256, 0, stream>>>(batch, sg, eg);

    const float* bs[4] = { b1, b2, b3, b4 };
    unsigned* cur = hA;
    unsigned* nxt = hB;
    for (int L = 0; L < 4; ++L) {
        k_aggregate<<<Nn / 4, 256, 0, stream>>>(cur, rowstart, recs, agg);
        k_transform<<<(Nn + 63) / 64, 256, 0, stream>>>(
            (const uint4*)agg, bhiA + (size_t)L * 20480, bloA + (size_t)L * 20480,
            bs[L], nxt);
        unsigned* tmp = cur; cur = nxt; nxt = tmp;
    }

    k_pool<<<Gg, 256, 0, stream>>>(cur, sg, eg, pooled);
    k_head<<<Gg, 128, 0, stream>>>(pooled, gamma, beta, mean, var, fcw, fcb, out);
}

// Round 10
// 545.850 us; speedup vs baseline: 1.2226x; 1.0546x over previous
//
#include <hip/hip_runtime.h>

// GNNML3 forward. R10: CSR build rewritten as two-level bucket sort.
//   k_bucket: append edge record to bucket dst>>6 (782 padded counters; tail
//             sectors L2-hot -> merged writes), dst low 6 bits packed in rec.
//   k_prefix: 782-bucket exclusive scan -> bucket bases.
//   k_sortbucket: per-bucket LDS sort (64-bin hist+scan+scatter), emits final
//             dst-sorted recs AND rowstart[] for free.
// Deletes k_rank (64us atomic floor), k_place (73us random write), 3-phase scan.
// Bucket staging region aliases agg (disjoint liveness).

#define Nn   50000
#define Ne   1600000
#define Gg   128
#define NEk  5
#define NINf 16
#define NCLSo 6
#define NBKT 782        // ceil(Nn/64)
#define SLACK 2544      // bucket region capacity (mean 2046, +11 sigma)
#define SPAD 41         // uint4 row stride of LDS A-tile in transform

using short8 = __attribute__((ext_vector_type(8))) short;
using f32x4  = __attribute__((ext_vector_type(4))) float;

__device__ __forceinline__ float2 bf2u(unsigned u) {
    return make_float2(__uint_as_float(u << 16), __uint_as_float(u & 0xffff0000u));
}
__device__ __forceinline__ unsigned f2bf(float a, float b) {
    unsigned ua = __float_as_uint(a), ub = __float_as_uint(b);
    ua += 0x7fffu + ((ua >> 16) & 1u);
    ub += 0x7fffu + ((ub >> 16) & 1u);
    return (ua >> 16) | (ub & 0xffff0000u);
}
__device__ __forceinline__ unsigned short f2bf1(float a) {
    unsigned ua = __float_as_uint(a);
    ua += 0x7fffu + ((ua >> 16) & 1u);
    return (unsigned short)(ua >> 16);
}

// ---------------- prep kernels ----------------

// x [Nn][16] fp32 -> h0 [Nn][32] uint (bf16x2 pairs, features >=16 zero)
__global__ void k_pad_x(const float* __restrict__ x, unsigned* __restrict__ h0) {
    int i = blockIdx.x * 256 + threadIdx.x;           // over Nn*32
    if (i >= Nn * 32) return;
    int n = i >> 5, p = i & 31;
    int f0 = 2 * p;
    float v0 = (f0 < NINf) ? x[n * NINf + f0] : 0.f;
    float v1 = (f0 + 1 < NINf) ? x[n * NINf + f0 + 1] : 0.f;
    h0[i] = f2bf(v0, v1);
}

__global__ void k_pad_w1(const float* __restrict__ W1, float* __restrict__ W1p) {
    int i = blockIdx.x * 256 + threadIdx.x;           // over 5*64*64
    if (i >= NEk * 64 * 64) return;
    int h = i & 63, f = (i >> 6) & 63, k = i >> 12;
    W1p[i] = (f < NINf) ? W1[(k * NINf + f) * 64 + h] : 0.f;
}

// pack W[320][64] fp32 into MFMA B-fragment layout, split hi/lo bf16.
__global__ void k_pack_b(const float* __restrict__ W, unsigned short* __restrict__ bhi,
                         unsigned short* __restrict__ blo) {
    int i = blockIdx.x * 256 + threadIdx.x;
    if (i >= 20480) return;
    int j = i & 7, lane = (i >> 3) & 63, t2 = i >> 9;   // t2 = nt*10+kstep
    int nt = t2 / 10, kstep = t2 - nt * 10;
    int k = kstep * 32 + (lane >> 4) * 8 + j;
    int col = nt * 16 + (lane & 15);
    float v = W[k * 64 + col];
    unsigned short hi = f2bf1(v);
    float fhi = __uint_as_float(((unsigned)hi) << 16);
    bhi[i] = hi;
    blo[i] = f2bf1(v - fhi);
}

// -------- two-level bucket CSR build --------

// append record {src, a01, a23, a4 | dst6<<16} to bucket dst>>6
__global__ void k_bucket(const int* __restrict__ ei, const float* __restrict__ eattr,
                         int* __restrict__ bcnt, uint4* __restrict__ region) {
    int e = blockIdx.x * 256 + threadIdx.x;
    if (e >= Ne) return;
    int d = ei[Ne + e];
    int b = d >> 6;
    int pos = atomicAdd(&bcnt[b * 16], 1);
    if (pos >= SLACK) return;                         // ~11 sigma, effectively never
    const float* a = eattr + (size_t)e * 5;
    uint4 r;
    r.x = (unsigned)ei[e];
    r.y = f2bf(a[0], a[1]);
    r.z = f2bf(a[2], a[3]);
    r.w = f2bf(a[4], 0.f) | ((unsigned)(d & 63) << 16);
    region[(size_t)b * SLACK + pos] = r;
}

// exclusive scan of 782 bucket counts -> bbase[0..NBKT]; rowstart[Nn] = Ne
__global__ void k_prefix(const int* __restrict__ bcnt, int* __restrict__ bbase,
                         int* __restrict__ rowstart) {
    __shared__ int l[1024];
    int t = threadIdx.x;
    int v = (t < NBKT) ? min(bcnt[t * 16], SLACK) : 0;
    l[t] = v;
    __syncthreads();
    for (int off = 1; off < 1024; off <<= 1) {
        int u = (t >= off) ? l[t - off] : 0;
        __syncthreads();
        l[t] += u;
        __syncthreads();
    }
    if (t < NBKT) bbase[t] = l[t] - v;                // exclusive
    if (t == 0) { bbase[NBKT] = l[1023]; rowstart[Nn] = l[1023]; }
}

// per-bucket LDS sort: 64-bin histogram + scan + scatter; emits rowstart too.
__global__ __launch_bounds__(256) void k_sortbucket(
    const uint4* __restrict__ region, const int* __restrict__ bcnt,
    const int* __restrict__ bbase, uint4* __restrict__ recs,
    int* __restrict__ rowstart) {
    __shared__ uint4 lrec[SLACK];                      // 40704 B
    __shared__ int hist[64], scn[64], cur[64];
    int b = blockIdx.x, t = threadIdx.x;
    int n = min(bcnt[b * 16], SLACK);
    int base = bbase[b];
    if (t < 64) hist[t] = 0;
    __syncthreads();
    for (int i = t; i < n; i += 256) {
        uint4 r = region[(size_t)b * SLACK + i];
        lrec[i] = r;
        atomicAdd(&hist[(r.w >> 16) & 63], 1);
    }
    __syncthreads();
    if (t == 0) {
        int s = 0;
        for (int j = 0; j < 64; ++j) { scn[j] = s; s += hist[j]; }
    }
    __syncthreads();
    if (t < 64) {
        cur[t] = scn[t];
        int node = b * 64 + t;
        if (node < Nn) rowstart[node] = base + scn[t];
    }
    __syncthreads();
    for (int i = t; i < n; i += 256) {
        uint4 r = lrec[i];
        int pos = atomicAdd(&cur[(r.w >> 16) & 63], 1);
        recs[(size_t)base + pos] = r;                  // within 40KB range: L2-hot
    }
}

// batch is sorted -> segment bounds by boundary detection
__global__ void k_bounds(const int* __restrict__ batch, int* __restrict__ sg,
                         int* __restrict__ eg) {
    int n = blockIdx.x * 256 + threadIdx.x;
    if (n >= Nn) return;
    int g = batch[n];
    if (n == 0) sg[g] = 0;
    else {
        int gp = batch[n - 1];
        if (gp != g) { sg[g] = n; eg[gp] = n; }
    }
    if (n == Nn - 1) eg[g] = Nn;
}

// ---------------- per-layer kernels ----------------

// one wave per node; half-wave (32 lanes) per edge, 2 features (bf16x2) per lane.
// unroll x8 -> 16 edges (8 independent recs->gather chains per half) in flight.
__global__ __launch_bounds__(256) void k_aggregate(
    const unsigned* __restrict__ hin, const int* __restrict__ rowstart,
    const uint4* __restrict__ recs, unsigned* __restrict__ agg) {
    int lane = threadIdx.x & 63;
    int l = lane & 31, half = lane >> 5;
    int node = __builtin_amdgcn_readfirstlane((int)(blockIdx.x * 4 + (threadIdx.x >> 6)));
    int beg = rowstart[node], end = rowstart[node + 1];
    float2 c0 = {0.f, 0.f}, c1 = c0, c2 = c0, c3 = c0, c4 = c0;
    int ee = beg;
#define EDGE(E) { \
    uint4 r = recs[(E)]; \
    unsigned hx = hin[(size_t)(int)r.x * 32 + l]; \
    float2 xv = bf2u(hx); \
    float2 A01 = bf2u(r.y), A23 = bf2u(r.z); \
    float a4v = __uint_as_float(r.w << 16); \
    c0.x = fmaf(A01.x, xv.x, c0.x); c0.y = fmaf(A01.x, xv.y, c0.y); \
    c1.x = fmaf(A01.y, xv.x, c1.x); c1.y = fmaf(A01.y, xv.y, c1.y); \
    c2.x = fmaf(A23.x, xv.x, c2.x); c2.y = fmaf(A23.x, xv.y, c2.y); \
    c3.x = fmaf(A23.y, xv.x, c3.x); c3.y = fmaf(A23.y, xv.y, c3.y); \
    c4.x = fmaf(a4v,  xv.x, c4.x); c4.y = fmaf(a4v,  xv.y, c4.y); }
    for (; ee + 16 <= end; ee += 16) {
        EDGE(ee + half)      EDGE(ee + 2 + half)  EDGE(ee + 4 + half)  EDGE(ee + 6 + half)
        EDGE(ee + 8 + half)  EDGE(ee + 10 + half) EDGE(ee + 12 + half) EDGE(ee + 14 + half)
    }
    for (; ee + 4 <= end; ee += 4) { EDGE(ee + half) EDGE(ee + 2 + half) }
    for (; ee + 2 <= end; ee += 2) { EDGE(ee + half) }
    if (ee < end) { if (half == 0) { EDGE(ee) } }
#undef EDGE
    // fold half 1 into half 0 (xor-butterfly, both halves end with the total)
    c0.x += __shfl(c0.x, lane ^ 32); c0.y += __shfl(c0.y, lane ^ 32);
    c1.x += __shfl(c1.x, lane ^ 32); c1.y += __shfl(c1.y, lane ^ 32);
    c2.x += __shfl(c2.x, lane ^ 32); c2.y += __shfl(c2.y, lane ^ 32);
    c3.x += __shfl(c3.x, lane ^ 32); c3.y += __shfl(c3.y, lane ^ 32);
    c4.x += __shfl(c4.x, lane ^ 32); c4.y += __shfl(c4.y, lane ^ 32);
    if (half == 0) {
        unsigned* o = agg + (size_t)node * 160 + l;
        o[0]   = f2bf(c0.x, c0.y);
        o[32]  = f2bf(c1.x, c1.y);
        o[64]  = f2bf(c2.x, c2.y);
        o[96]  = f2bf(c3.x, c3.y);
        o[128] = f2bf(c4.x, c4.y);
    }
}

// MFMA transform: [64 nodes x 320]bf16 x (Whi+Wlo)[320 x 64] + bias, relu -> bf16.
__global__ __launch_bounds__(256) void k_transform(
    const uint4* __restrict__ A, const unsigned short* __restrict__ bhi,
    const unsigned short* __restrict__ blo, const float* __restrict__ bias,
    unsigned* __restrict__ outh) {
    __shared__ uint4 smem[64 * SPAD];                  // 41984 B
    int t = threadIdx.x;
    int lane = t & 63, wave = t >> 6;
    int m = lane & 15, quad = lane >> 4;
    int blk = blockIdx.x;

#pragma unroll
    for (int it = 0; it < 10; ++it) {
        int v = t + it * 256;                          // 0..2559
        int row = v / 40, off = v - row * 40;
        int node = blk * 64 + row;
        if (node >= Nn) node = Nn - 1;
        smem[row * SPAD + off] = A[(size_t)node * 40 + off];
    }
    __syncthreads();

    f32x4 acc0 = {0.f, 0.f, 0.f, 0.f}, acc1 = acc0, acc2 = acc0, acc3 = acc0;
    const uint4* arow = smem + (wave * 16 + m) * SPAD + quad;
#pragma unroll 2
    for (int ks = 0; ks < 10; ++ks) {
        short8 a = *(const short8*)(arow + ks * 4);
        size_t bb = ((size_t)ks * 64 + lane) * 8;      // + nt*5120
        short8 h0 = *(const short8*)(bhi + bb);
        short8 l0 = *(const short8*)(blo + bb);
        acc0 = __builtin_amdgcn_mfma_f32_16x16x32_bf16(a, h0, acc0, 0, 0, 0);
        acc0 = __builtin_amdgcn_mfma_f32_16x16x32_bf16(a, l0, acc0, 0, 0, 0);
        short8 h1 = *(const short8*)(bhi + bb + 5120);
        short8 l1 = *(const short8*)(blo + bb + 5120);
        acc1 = __builtin_amdgcn_mfma_f32_16x16x32_bf16(a, h1, acc1, 0, 0, 0);
        acc1 = __builtin_amdgcn_mfma_f32_16x16x32_bf16(a, l1, acc1, 0, 0, 0);
        short8 h2 = *(const short8*)(bhi + bb + 10240);
        short8 l2 = *(const short8*)(blo + bb + 10240);
        acc2 = __builtin_amdgcn_mfma_f32_16x16x32_bf16(a, h2, acc2, 0, 0, 0);
        acc2 = __builtin_amdgcn_mfma_f32_16x16x32_bf16(a, l2, acc2, 0, 0, 0);
        short8 h3 = *(const short8*)(bhi + bb + 15360);
        short8 l3 = *(const short8*)(blo + bb + 15360);
        acc3 = __builtin_amdgcn_mfma_f32_16x16x32_bf16(a, h3, acc3, 0, 0, 0);
        acc3 = __builtin_amdgcn_mfma_f32_16x16x32_bf16(a, l3, acc3, 0, 0, 0);
    }
    __syncthreads();                                   // A-tile reads done

    // C layout (16x16x32): col=lane&15, row=quad*4+reg -> spill to LDS fp32 [64][72]
    float* Cs = (float*)smem;
#pragma unroll
    for (int r = 0; r < 4; ++r) {
        int base = wave * 1152 + (quad * 4 + r) * 72 + m;
        Cs[base]      = acc0[r];
        Cs[base + 16] = acc1[r];
        Cs[base + 32] = acc2[r];
        Cs[base + 48] = acc3[r];
    }
    __syncthreads();

    int row = t >> 2, grp = t & 3;                     // 4 threads/row, 8 uints each
    int node = blk * 64 + row;
    if (node < Nn) {
        const float* cr = Cs + (row >> 4) * 1152 + (row & 15) * 72;
        unsigned o[8];
#pragma unroll
        for (int j = 0; j < 8; ++j) {
            int pp = grp * 8 + j;
            float v0 = fmaxf(cr[2 * pp]     + bias[2 * pp],     0.f);
            float v1 = fmaxf(cr[2 * pp + 1] + bias[2 * pp + 1], 0.f);
            o[j] = f2bf(v0, v1);
        }
        uint4* dst = (uint4*)(outh + (size_t)node * 32 + grp * 8);
        dst[0] = make_uint4(o[0], o[1], o[2], o[3]);
        dst[1] = make_uint4(o[4], o[5], o[6], o[7]);
    }
}

// ---------------- pooling + head ----------------

__global__ __launch_bounds__(256) void k_pool(const unsigned* __restrict__ h,
                                              const int* __restrict__ sg,
                                              const int* __restrict__ eg,
                                              float* __restrict__ pooled) {
    __shared__ float2 ls[256], lm[256];
    int g = blockIdx.x, t = threadIdx.x;
    int p = t & 31, q = t >> 5;                        // 32 feature-pairs x 8 node-strides
    int s = sg[g], e = eg[g];
    float2 sum = {0.f, 0.f}, mx = {0.f, 0.f};          // relu>=0 -> 0 valid max identity
    for (int n = s + q; n < e; n += 8) {
        float2 v = bf2u(h[(size_t)n * 32 + p]);
        sum.x += v.x; sum.y += v.y;
        mx.x = fmaxf(mx.x, v.x); mx.y = fmaxf(mx.y, v.y);
    }
    ls[t] = sum; lm[t] = mx;
    __syncthreads();
    if (t < 32) {
        float2 ss = ls[t], mm = lm[t];
        for (int i = 1; i < 8; ++i) {
            float2 a = ls[t + i * 32], b = lm[t + i * 32];
            ss.x += a.x; ss.y += a.y;
            mm.x = fmaxf(mm.x, b.x); mm.y = fmaxf(mm.y, b.y);
        }
        pooled[g * 128 + 2 * t]          = ss.x;
        pooled[g * 128 + 2 * t + 1]      = ss.y;
        pooled[g * 128 + 64 + 2 * t]     = mm.x;
        pooled[g * 128 + 64 + 2 * t + 1] = mm.y;
    }
}

__global__ void k_head(const float* __restrict__ pooled, const float* __restrict__ gamma,
                       const float* __restrict__ beta, const float* __restrict__ mean,
                       const float* __restrict__ var, const float* __restrict__ fcw,
                       const float* __restrict__ fcb, float* __restrict__ out) {
    __shared__ float y[128];
    __shared__ float lg[8];
    int g = blockIdx.x, c = threadIdx.x;   // 128 threads
    float p = pooled[g * 128 + c];
    y[c] = (p - mean[c]) * rsqrtf(var[c] + 1e-5f) * gamma[c] + beta[c];
    __syncthreads();
    if (c < NCLSo) {
        float l = fcb[c];
        for (int i = 0; i < 128; ++i) l += y[i] * fcw[i * NCLSo + c];
        lg[c] = l;
    }
    __syncthreads();
    if (c == 0) {
        float m = lg[0];
        for (int j = 1; j < NCLSo; ++j) m = fmaxf(m, lg[j]);
        float se = 0.f;
        for (int j = 0; j < NCLSo; ++j) se += expf(lg[j] - m);
        float lse = m + logf(se);
        for (int j = 0; j < NCLSo; ++j) out[g * NCLSo + j] = lg[j] - lse;
    }
}

// ---------------- launch ----------------

static inline size_t rup(size_t x) { return (x + 255) & ~(size_t)255; }

extern "C" void kernel_launch(void* const* d_in, const int* in_sizes, int n_in,
                              void* d_out, int out_size, void* d_ws, size_t ws_size,
                              hipStream_t stream) {
    const float* x     = (const float*)d_in[0];
    const int*   ei    = (const int*)d_in[1];
    const float* eattr = (const float*)d_in[2];
    const int*   batch = (const int*)d_in[3];
    const float* W1    = (const float*)d_in[4];
    const float* b1    = (const float*)d_in[5];
    const float* W2    = (const float*)d_in[6];
    const float* b2    = (const float*)d_in[7];
    const float* W3    = (const float*)d_in[8];
    const float* b3    = (const float*)d_in[9];
    const float* W4    = (const float*)d_in[10];
    const float* b4    = (const float*)d_in[11];
    const float* gamma = (const float*)d_in[12];
    const float* beta  = (const float*)d_in[13];
    const float* mean  = (const float*)d_in[14];
    const float* var   = (const float*)d_in[15];
    const float* fcw   = (const float*)d_in[16];
    const float* fcb   = (const float*)d_in[17];
    float* out = (float*)d_out;

    char* p = (char*)d_ws;
    auto take = [&](size_t bytes) { char* r = p; p += rup(bytes); return r; };
    int*            bcnt     = (int*)take((size_t)NBKT * 64);        // padded counters
    int*            bbase    = (int*)take((size_t)(NBKT + 1) * 4);
    int*            rowstart = (int*)take((size_t)(Nn + 1) * 4);
    uint4*          recs     = (uint4*)take((size_t)Ne * 16);
    unsigned*       hA       = (unsigned*)take((size_t)Nn * 32 * 4);
    unsigned*       hB       = (unsigned*)take((size_t)Nn * 32 * 4);
    unsigned*       agg      = (unsigned*)take((size_t)Nn * 160 * 4); // aliased: region
    float*          W1p      = (float*)take((size_t)NEk * 64 * 64 * 4);
    unsigned short* bhiA     = (unsigned short*)take((size_t)4 * 20480 * 2);
    unsigned short* bloA     = (unsigned short*)take((size_t)4 * 20480 * 2);
    float*          pooled   = (float*)take((size_t)Gg * 128 * 4);
    int*            sg       = (int*)take((size_t)Gg * 4);
    int*            eg       = (int*)take((size_t)Gg * 4);

    uint4* region = (uint4*)agg;   // NBKT*SLACK*16 = 31.83 MB <= agg 32.0 MB; dead
                                   // before first k_aggregate writes agg.

    (void)hipMemsetAsync(bcnt, 0, (size_t)NBKT * 64, stream);

    k_pad_x<<<(Nn * 32 + 255) / 256, 256, 0, stream>>>(x, hA);
    k_pad_w1<<<(NEk * 64 * 64 + 255) / 256, 256, 0, stream>>>(W1, W1p);
    k_pack_b<<<80, 256, 0, stream>>>(W1p, bhiA,             bloA);
    k_pack_b<<<80, 256, 0, stream>>>(W2,  bhiA + 20480,     bloA + 20480);
    k_pack_b<<<80, 256, 0, stream>>>(W3,  bhiA + 2 * 20480, bloA + 2 * 20480);
    k_pack_b<<<80, 256, 0, stream>>>(W4,  bhiA + 3 * 20480, bloA + 3 * 20480);
    k_bucket<<<(Ne + 255) / 256, 256, 0, stream>>>(ei, eattr, bcnt, region);
    k_prefix<<<1, 1024, 0, stream>>>(bcnt, bbase, rowstart);
    k_sortbucket<<<NBKT, 256, 0, stream>>>(region, bcnt, bbase, recs, rowstart);
    k_bounds<<<(Nn + 255) / 256, 256, 0, stream>>>(batch, sg, eg);

    const float* bs[4] = { b1, b2, b3, b4 };
    unsigned* cur = hA;
    unsigned* nxt = hB;
    for (int L = 0; L < 4; ++L) {
        k_aggregate<<<Nn / 4, 256, 0, stream>>>(cur, rowstart, recs, agg);
        k_transform<<<(Nn + 63) / 64, 256, 0, stream>>>(
            (const uint4*)agg, bhiA + (size_t)L * 20480, bloA + (size_t)L * 20480,
            bs[L], nxt);
        unsigned* tmp = cur; cur = nxt; nxt = tmp;
    }

    k_pool<<<Gg, 256, 0, stream>>>(cur, sg, eg, pooled);
    k_head<<<Gg, 128, 0, stream>>>(pooled, gamma, beta, mean, var, fcw, fcb, out);
}